// Round 13
// baseline (230.577 us; speedup 1.0000x reference)
//
#include <hip/hip_runtime.h>

#define N_NODES 100000
#define N_EDGES 1200000
#define BK 64                     // nodes per bucket
#define NB 1563                   // ceil(100000/64)
#define CHUNK_E 4096
#define NBLK_E 293                // ceil(N_EDGES / CHUNK_E)
#define TOT_H (NB * NBLK_E)       // 457959
#define NSB2 ((TOT_H + 1023) / 1024)   // 448
#define CAP 1536                  // LDS edge-list capacity (expected ~768 +- 28)
#define ND1 3125                  // dense1 blocks (32 nodes each)

// Workspace layout (bytes), ~56.6 MB. y2 gets its OWN slot: K4 now writes y2
// while still READING y1 (other blocks' gathers), so they must not alias.
#define OFF_ROWPTR 0
#define OFF_HISTG  401408
#define OFF_BLK2   2234368
#define OFF_PAIRS  2236416
#define OFF_SORTED 7036928
#define OFF_Y1     11837440
#define OFF_H1     24637440
#define OFF_Y2     50237440

__device__ __forceinline__ unsigned short f2bf(float f) {
    unsigned u = __float_as_uint(f);
    unsigned r = (u + 0x7fffu + ((u >> 16) & 1u)) >> 16;   // RNE
    return (unsigned short)r;
}

// ---- K1: chunk_hist (blocks 0..292) + dense1 (blocks 293..3417) fused ----
// Round-6 structure: best of 8 variants (~85% of the 103 TF f32 roofline for
// dense1's 3.28 GFLOP). MFMA role-split variants (r4-r11) all lost.
__global__ __launch_bounds__(256) void hist_dense1_kernel(
    const int* __restrict__ dst, int* __restrict__ hist_g,
    const float* __restrict__ x,
    const float* __restrict__ Wn, const float* __restrict__ Ws,
    const float* __restrict__ b,
    unsigned short* __restrict__ y1, float* __restrict__ z1)
{
    __shared__ float sx[32 * 64];   // 8 KB; hist part reuses as int h[NB] (1563 <= 2048)
    const int t = threadIdx.x;

    if (blockIdx.x < NBLK_E) {
        int* h = (int*)sx;
        const int e0 = blockIdx.x * CHUNK_E;
        const int e1 = min(e0 + CHUNK_E, N_EDGES);
        for (int i = t; i < NB; i += 256) h[i] = 0;
        __syncthreads();
        for (int e = e0 + t; e < e1; e += 256)
            atomicAdd(&h[dst[e] >> 6], 1);
        __syncthreads();
        for (int i = t; i < NB; i += 256)
            hist_g[i * NBLK_E + blockIdx.x] = h[i];
        return;
    }

    const int bid = blockIdx.x - NBLK_E;
    const int w = t >> 6;
    const int lane = t & 63;
    const int half = w >> 1;
    const int nsub = (w & 1) * 16;
    const int chunk = bid * 32;

    {
        const float4* gx = (const float4*)(x + (size_t)chunk * 64);
        float4* sx4 = (float4*)sx;
        sx4[t] = gx[t];
        sx4[t + 256] = gx[t + 256];
    }

    const float* W = half ? Ws : Wn;
    float wr[64];
#pragma unroll
    for (int k = 0; k < 64; ++k) wr[k] = W[k * 64 + lane];
    const float bj = half ? b[lane] : 0.f;

    __syncthreads();

#pragma unroll 2
    for (int m = 0; m < 16; ++m) {
        const int node = nsub + m;
        const float4* xr = (const float4*)(sx + node * 64);
        float a0 = 0.f, a1 = 0.f, a2 = 0.f, a3 = 0.f;
#pragma unroll
        for (int k4 = 0; k4 < 16; ++k4) {
            float4 v = xr[k4];
            a0 += v.x * wr[4 * k4 + 0];
            a1 += v.y * wr[4 * k4 + 1];
            a2 += v.z * wr[4 * k4 + 2];
            a3 += v.w * wr[4 * k4 + 3];
        }
        const float o = (a0 + a1) + (a2 + a3) + bj;
        const size_t gn = (size_t)(chunk + node);
        if (half) z1[gn * 64 + lane] = o;
        else      y1[gn * 64 + lane] = f2bf(o);
    }
}

// ---- K2: block-local scan of hist_g IN PLACE via wave-shuffle ----
__global__ __launch_bounds__(1024) void scan2_blocks_kernel(
    int* __restrict__ hist_g, int* __restrict__ blk2)
{
    __shared__ int wsum[16];
    const int t = threadIdx.x;
    const int i = blockIdx.x * 1024 + t;
    const int v = (i < TOT_H) ? hist_g[i] : 0;
    int inc = v;
#pragma unroll
    for (int off = 1; off < 64; off <<= 1) {
        int n = __shfl_up(inc, off);
        if ((t & 63) >= off) inc += n;
    }
    const int wid = t >> 6;                 // 0..15
    if ((t & 63) == 63) wsum[wid] = inc;
    __syncthreads();
    if (t < 16) {
        int s = wsum[t];
#pragma unroll
        for (int off = 1; off < 16; off <<= 1) {
            int n = __shfl_up(s, off);
            if (t >= off) s += n;
        }
        wsum[t] = s;
    }
    __syncthreads();
    const int base = (wid > 0) ? wsum[wid - 1] : 0;
    const int incl = inc + base;
    if (i < TOT_H) hist_g[i] = incl - v;    // exclusive
    if (t == 1023) blk2[blockIdx.x] = incl; // block total
}

// ---- K2b: single-block exclusive scan of blk2 IN PLACE (wave-shuffle) ----
__global__ __launch_bounds__(512) void tops_scan_kernel(int* __restrict__ blk2)
{
    __shared__ int wsum[8];
    const int t = threadIdx.x;
    const int v = (t < NSB2) ? blk2[t] : 0;
    int inc = v;
#pragma unroll
    for (int off = 1; off < 64; off <<= 1) {
        int n = __shfl_up(inc, off);
        if ((t & 63) >= off) inc += n;
    }
    const int wid = t >> 6;                 // 0..7
    if ((t & 63) == 63) wsum[wid] = inc;
    __syncthreads();
    if (t < 8) {
        int s = wsum[t];
#pragma unroll
        for (int off = 1; off < 8; off <<= 1) {
            int n = __shfl_up(s, off);
            if (t >= off) s += n;
        }
        wsum[t] = s;
    }
    __syncthreads();
    const int base = (wid > 0) ? wsum[wid - 1] : 0;
    if (t < NSB2) blk2[t] = inc + base - v; // exclusive prefix
}

// ---- K3: deterministic pair scatter (blk2 holds pre-scanned tops) ----
__global__ __launch_bounds__(512) void pair_scatter_kernel(
    const int* __restrict__ src, const int* __restrict__ dst,
    const int* __restrict__ hs_scan, const int* __restrict__ blk2,
    unsigned* __restrict__ pairs)
{
    __shared__ int base_s[NB];
    __shared__ int cur_s[NB];
    const int b = blockIdx.x;
    const int t = threadIdx.x;
    const int e0 = b * CHUNK_E;
    const int e1 = min(e0 + CHUNK_E, N_EDGES);

    for (int i = t; i < NB; i += 512) {
        int idx = i * NBLK_E + b;
        base_s[i] = hs_scan[idx] + blk2[idx >> 10];
        cur_s[i] = 0;
    }
    __syncthreads();
    for (int e = e0 + t; e < e1; e += 512) {
        int d = dst[e];
        int bk = d >> 6;
        int pos = base_s[bk] + atomicAdd(&cur_s[bk], 1);
        pairs[pos] = ((unsigned)src[e] << 6) | (unsigned)(d & 63);
    }
}

// ---- K4: fused bucket sort + gather1 + DENSE2 (K5 folded in) ----
// After the d=8,16 reduce every lane of a 32-lane node group holds the full
// neighbor sums a0..a7 for its fl. ReLU(z + mean) in registers, then each
// lane does an 8x4 partial dot vs LDS-staged W2 ([64][17] pad -> ~2-way
// conflicts, free per m136), reduce over fl (shfl_xor 1,2,4), fl==0 writes
// y2/out. Kills K5: h1 round-trip (25.6 MB) + a launch.
__global__ __launch_bounds__(512) void fused_gather1_kernel(
    const unsigned short* __restrict__ y1,
    const unsigned* __restrict__ pairs,
    const int* __restrict__ hs_scan, const int* __restrict__ blk2,
    const float* __restrict__ h1,
    const float* __restrict__ W2n, const float* __restrict__ W2s,
    const float* __restrict__ b2,
    int* __restrict__ row_ptr, int* __restrict__ sorted_src,
    float* __restrict__ y2, float* __restrict__ outp)
{
    __shared__ int slist[CAP];
    __shared__ int hist[BK];
    __shared__ int sc[BK];
    __shared__ int cur[BK];
    __shared__ float sW2n[64 * 17];
    __shared__ float sW2s[64 * 17];
    const int b = blockIdx.x;
    const int t = threadIdx.x;

    for (int e = t; e < 1024; e += 512) {
        sW2n[(e >> 4) * 17 + (e & 15)] = W2n[e];
        sW2s[(e >> 4) * 17 + (e & 15)] = W2s[e];
    }

    const int i0 = b * NBLK_E;
    const int start = hs_scan[i0] + blk2[i0 >> 10];
    const int end = (b == NB - 1) ? N_EDGES
                    : hs_scan[i0 + NBLK_E] + blk2[(i0 + NBLK_E) >> 10];
    const int cnt = end - start;
    const int node0 = b * BK;

    if (t < BK) hist[t] = 0;
    __syncthreads();
    for (int e = start + t; e < end; e += 512)
        atomicAdd(&hist[pairs[e] & 63u], 1);
    __syncthreads();

    // 64-bin inclusive scan by wave 0 (BK == wavefront size), no barriers
    int v = 0;
    if (t < BK) {
        v = hist[t];
        int inc = v;
#pragma unroll
        for (int off = 1; off < 64; off <<= 1) {
            int n = __shfl_up(inc, off);
            if (t >= off) inc += n;
        }
        sc[t] = inc;
    }
    __syncthreads();
    const int excl = (t < BK) ? sc[t] - v : 0;
    if (t < BK && node0 + t < N_NODES) row_ptr[node0 + t] = start + excl;
    if (b == NB - 1 && t == 0) row_ptr[N_NODES] = N_EDGES;
    if (t < BK) cur[t] = excl;
    __syncthreads();

    const int wv = t >> 6;
    const int lane = t & 63;
    const int sub = lane >> 5;        // 2 nodes per wave
    const int sl = lane & 31;
    const int eg = sl >> 3;           // 4 edge slots
    const int fl = sl & 7;            // uint4 chunk of the 128 B y1 row
    const float4 bb = ((const float4*)b2)[eg];

    if (cnt <= CAP) {
        for (int e = start + t; e < end; e += 512) {
            unsigned u = pairs[e];
            int p = atomicAdd(&cur[u & 63u], 1);
            slist[p] = (int)(u >> 6);
        }
        __syncthreads();
        for (int i = t; i < cnt; i += 512)
            sorted_src[start + i] = slist[i];
        for (int q = 0; q < 4; ++q) {
            const int node = wv * 8 + q * 2 + sub;
            const int gn = node0 + node;
            if (gn >= N_NODES) break;
            const int o = sc[node] - hist[node];
            const int dg = hist[node];
            const float4* hp = (const float4*)(h1 + (size_t)gn * 64);
            const float4 z0 = hp[fl * 2];          // self part, all lanes
            const float4 z1v = hp[fl * 2 + 1];
            float a0 = 0.f, a1 = 0.f, a2 = 0.f, a3 = 0.f;
            float a4 = 0.f, a5 = 0.f, a6 = 0.f, a7 = 0.f;
            for (int base = 0; base < dg; base += 8) {
                const int i0e = base + eg;
                const int i1e = base + 4 + eg;
                const bool v0 = i0e < dg, v1 = i1e < dg;
                uint4 r0, r1;
                if (v0) {
                    const int s = slist[o + i0e];
                    r0 = ((const uint4*)(y1 + (size_t)s * 64))[fl];
                }
                if (v1) {
                    const int s = slist[o + i1e];
                    r1 = ((const uint4*)(y1 + (size_t)s * 64))[fl];
                }
                if (v0) {
                    a0 += __uint_as_float(r0.x << 16);
                    a1 += __uint_as_float(r0.x & 0xffff0000u);
                    a2 += __uint_as_float(r0.y << 16);
                    a3 += __uint_as_float(r0.y & 0xffff0000u);
                    a4 += __uint_as_float(r0.z << 16);
                    a5 += __uint_as_float(r0.z & 0xffff0000u);
                    a6 += __uint_as_float(r0.w << 16);
                    a7 += __uint_as_float(r0.w & 0xffff0000u);
                }
                if (v1) {
                    a0 += __uint_as_float(r1.x << 16);
                    a1 += __uint_as_float(r1.x & 0xffff0000u);
                    a2 += __uint_as_float(r1.y << 16);
                    a3 += __uint_as_float(r1.y & 0xffff0000u);
                    a4 += __uint_as_float(r1.z << 16);
                    a5 += __uint_as_float(r1.z & 0xffff0000u);
                    a6 += __uint_as_float(r1.w << 16);
                    a7 += __uint_as_float(r1.w & 0xffff0000u);
                }
            }
#pragma unroll
            for (int d = 8; d <= 16; d <<= 1) {
                a0 += __shfl_xor(a0, d); a1 += __shfl_xor(a1, d);
                a2 += __shfl_xor(a2, d); a3 += __shfl_xor(a3, d);
                a4 += __shfl_xor(a4, d); a5 += __shfl_xor(a5, d);
                a6 += __shfl_xor(a6, d); a7 += __shfl_xor(a7, d);
            }
            const float invd = 1.0f / (float)max(dg, 1);
            float hv[8];
            hv[0] = fmaxf(z0.x + a0 * invd, 0.f);
            hv[1] = fmaxf(z0.y + a1 * invd, 0.f);
            hv[2] = fmaxf(z0.z + a2 * invd, 0.f);
            hv[3] = fmaxf(z0.w + a3 * invd, 0.f);
            hv[4] = fmaxf(z1v.x + a4 * invd, 0.f);
            hv[5] = fmaxf(z1v.y + a5 * invd, 0.f);
            hv[6] = fmaxf(z1v.z + a6 * invd, 0.f);
            hv[7] = fmaxf(z1v.w + a7 * invd, 0.f);
            float pn0 = 0.f, pn1 = 0.f, pn2 = 0.f, pn3 = 0.f;
            float ps0 = 0.f, ps1 = 0.f, ps2 = 0.f, ps3 = 0.f;
            const float* wnB = sW2n + (8 * fl) * 17 + eg * 4;
            const float* wsB = sW2s + (8 * fl) * 17 + eg * 4;
#pragma unroll
            for (int i = 0; i < 8; ++i) {
                const float h = hv[i];
                const float* wn = wnB + i * 17;
                const float* wsp = wsB + i * 17;
                pn0 += h * wn[0];  pn1 += h * wn[1];
                pn2 += h * wn[2];  pn3 += h * wn[3];
                ps0 += h * wsp[0]; ps1 += h * wsp[1];
                ps2 += h * wsp[2]; ps3 += h * wsp[3];
            }
#pragma unroll
            for (int d = 1; d <= 4; d <<= 1) {
                pn0 += __shfl_xor(pn0, d); pn1 += __shfl_xor(pn1, d);
                pn2 += __shfl_xor(pn2, d); pn3 += __shfl_xor(pn3, d);
                ps0 += __shfl_xor(ps0, d); ps1 += __shfl_xor(ps1, d);
                ps2 += __shfl_xor(ps2, d); ps3 += __shfl_xor(ps3, d);
            }
            if (fl == 0) {
                ((float4*)(y2 + (size_t)gn * 16))[eg] =
                    make_float4(pn0, pn1, pn2, pn3);
                ((float4*)(outp + (size_t)gn * 16))[eg] =
                    make_float4(ps0 + bb.x, ps1 + bb.y, ps2 + bb.z, ps3 + bb.w);
            }
        }
    } else {
        // fallback (statistically unreachable): global two-phase sort + gather
        if (t < BK) cur[t] = start + excl;
        __syncthreads();
        for (int e = start + t; e < end; e += 512) {
            unsigned u = pairs[e];
            int p = atomicAdd(&cur[u & 63u], 1);
            sorted_src[p] = (int)(u >> 6);
        }
        __syncthreads();
        for (int q = 0; q < 4; ++q) {
            const int node = wv * 8 + q * 2 + sub;
            const int gn = node0 + node;
            if (gn >= N_NODES) break;
            const int o = start + sc[node] - hist[node];
            const int dg = hist[node];
            const float4* hp = (const float4*)(h1 + (size_t)gn * 64);
            const float4 z0 = hp[fl * 2];
            const float4 z1v = hp[fl * 2 + 1];
            float a0 = 0.f, a1 = 0.f, a2 = 0.f, a3 = 0.f;
            float a4 = 0.f, a5 = 0.f, a6 = 0.f, a7 = 0.f;
            for (int base = 0; base < dg; base += 4) {
                const int idx = base + eg;
                if (idx < dg) {
                    const int s = sorted_src[o + idx];
                    uint4 raw = ((const uint4*)(y1 + (size_t)s * 64))[fl];
                    a0 += __uint_as_float(raw.x << 16);
                    a1 += __uint_as_float(raw.x & 0xffff0000u);
                    a2 += __uint_as_float(raw.y << 16);
                    a3 += __uint_as_float(raw.y & 0xffff0000u);
                    a4 += __uint_as_float(raw.z << 16);
                    a5 += __uint_as_float(raw.z & 0xffff0000u);
                    a6 += __uint_as_float(raw.w << 16);
                    a7 += __uint_as_float(raw.w & 0xffff0000u);
                }
            }
#pragma unroll
            for (int d = 8; d <= 16; d <<= 1) {
                a0 += __shfl_xor(a0, d); a1 += __shfl_xor(a1, d);
                a2 += __shfl_xor(a2, d); a3 += __shfl_xor(a3, d);
                a4 += __shfl_xor(a4, d); a5 += __shfl_xor(a5, d);
                a6 += __shfl_xor(a6, d); a7 += __shfl_xor(a7, d);
            }
            const float invd = 1.0f / (float)max(dg, 1);
            float hv[8];
            hv[0] = fmaxf(z0.x + a0 * invd, 0.f);
            hv[1] = fmaxf(z0.y + a1 * invd, 0.f);
            hv[2] = fmaxf(z0.z + a2 * invd, 0.f);
            hv[3] = fmaxf(z0.w + a3 * invd, 0.f);
            hv[4] = fmaxf(z1v.x + a4 * invd, 0.f);
            hv[5] = fmaxf(z1v.y + a5 * invd, 0.f);
            hv[6] = fmaxf(z1v.z + a6 * invd, 0.f);
            hv[7] = fmaxf(z1v.w + a7 * invd, 0.f);
            float pn0 = 0.f, pn1 = 0.f, pn2 = 0.f, pn3 = 0.f;
            float ps0 = 0.f, ps1 = 0.f, ps2 = 0.f, ps3 = 0.f;
            const float* wnB = sW2n + (8 * fl) * 17 + eg * 4;
            const float* wsB = sW2s + (8 * fl) * 17 + eg * 4;
#pragma unroll
            for (int i = 0; i < 8; ++i) {
                const float h = hv[i];
                const float* wn = wnB + i * 17;
                const float* wsp = wsB + i * 17;
                pn0 += h * wn[0];  pn1 += h * wn[1];
                pn2 += h * wn[2];  pn3 += h * wn[3];
                ps0 += h * wsp[0]; ps1 += h * wsp[1];
                ps2 += h * wsp[2]; ps3 += h * wsp[3];
            }
#pragma unroll
            for (int d = 1; d <= 4; d <<= 1) {
                pn0 += __shfl_xor(pn0, d); pn1 += __shfl_xor(pn1, d);
                pn2 += __shfl_xor(pn2, d); pn3 += __shfl_xor(pn3, d);
                ps0 += __shfl_xor(ps0, d); ps1 += __shfl_xor(ps1, d);
                ps2 += __shfl_xor(ps2, d); ps3 += __shfl_xor(ps3, d);
            }
            if (fl == 0) {
                ((float4*)(y2 + (size_t)gn * 16))[eg] =
                    make_float4(pn0, pn1, pn2, pn3);
                ((float4*)(outp + (size_t)gn * 16))[eg] =
                    make_float4(ps0 + bb.x, ps1 + bb.y, ps2 + bb.z, ps3 + bb.w);
            }
        }
    }
}

// ---- K6: gather2 — 4 nodes per wave (16 lanes/node), out-row prefetched ----
__global__ __launch_bounds__(256) void gather2_kernel(
    const float* __restrict__ y2,
    const int* __restrict__ row_ptr,
    const int* __restrict__ sorted_src,
    float* __restrict__ out)
{
    const int wv = threadIdx.x >> 6;
    const int lane = threadIdx.x & 63;
    const int sub = lane >> 4;        // node slot 0..3
    const int sl = lane & 15;         // lane within node group
    const int eg = sl >> 2;           // edge slot 0..3
    const int fl = sl & 3;            // float4 chunk of 16-f32 row

    const int n = blockIdx.x * 16 + wv * 4 + sub;   // grid 6250 -> exact
    const int start = row_ptr[n];
    const int deg = row_ptr[n + 1] - start;

    float4* op = (float4*)(out + (size_t)n * 16);
    float4 z;
    if (eg == 0) z = op[fl];          // prefetch self-part row early

    float4 acc = make_float4(0.f, 0.f, 0.f, 0.f);
    for (int base = 0; base < deg; base += 16) {
        int eid = 0;
        if (base + sl < deg) eid = sorted_src[start + base + sl];
#pragma unroll
        for (int jj = 0; jj < 16; jj += 4) {
            const int idx = jj + eg;
            const int s = __shfl(eid, sub * 16 + idx);
            if (base + idx < deg) {
                float4 v = ((const float4*)(y2 + (size_t)s * 16))[fl];
                acc.x += v.x; acc.y += v.y; acc.z += v.z; acc.w += v.w;
            }
        }
    }
#pragma unroll
    for (int d = 4; d <= 8; d <<= 1) {
        acc.x += __shfl_xor(acc.x, d); acc.y += __shfl_xor(acc.y, d);
        acc.z += __shfl_xor(acc.z, d); acc.w += __shfl_xor(acc.w, d);
    }
    const float invd = 1.0f / (float)max(deg, 1);
    if (eg == 0) {
        op[fl] = make_float4(z.x + acc.x * invd, z.y + acc.y * invd,
                             z.z + acc.z * invd, z.w + acc.w * invd);
    }
}

extern "C" void kernel_launch(void* const* d_in, const int* in_sizes, int n_in,
                              void* d_out, int out_size, void* d_ws, size_t ws_size,
                              hipStream_t stream) {
    const float* x   = (const float*)d_in[0];
    const int*   src = (const int*)d_in[1];
    const int*   dst = (const int*)d_in[2];
    const float* W1s = (const float*)d_in[3];
    const float* W1n = (const float*)d_in[4];
    const float* b1  = (const float*)d_in[5];
    const float* W2s = (const float*)d_in[6];
    const float* W2n = (const float*)d_in[7];
    const float* b2  = (const float*)d_in[8];
    float* out = (float*)d_out;

    char* ws = (char*)d_ws;
    int* row_ptr    = (int*)(ws + OFF_ROWPTR);
    int* hist_g     = (int*)(ws + OFF_HISTG);   // scanned in place by K2
    int* blk2       = (int*)(ws + OFF_BLK2);    // raw sums -> K2b scans in place
    unsigned* pairs = (unsigned*)(ws + OFF_PAIRS);
    int* sorted_src = (int*)(ws + OFF_SORTED);
    unsigned short* y1 = (unsigned short*)(ws + OFF_Y1);
    float* h1       = (float*)(ws + OFF_H1);    // self part only (K1); K4 reads
    float* y2       = (float*)(ws + OFF_Y2);    // own slot — y1 stays live in K4

    hist_dense1_kernel<<<NBLK_E + ND1, 256, 0, stream>>>(
        dst, hist_g, x, W1n, W1s, b1, y1, h1);
    scan2_blocks_kernel<<<NSB2, 1024, 0, stream>>>(hist_g, blk2);
    tops_scan_kernel<<<1, 512, 0, stream>>>(blk2);
    pair_scatter_kernel<<<NBLK_E, 512, 0, stream>>>(src, dst, hist_g, blk2, pairs);
    fused_gather1_kernel<<<NB, 512, 0, stream>>>(
        y1, pairs, hist_g, blk2, h1, W2n, W2s, b2,
        row_ptr, sorted_src, y2, out);
    gather2_kernel<<<N_NODES / 16, 256, 0, stream>>>(y2, row_ptr, sorted_src, out);
}

// Round 14
// 208.858 us; speedup vs baseline: 1.1040x; 1.1040x over previous
//
#include <hip/hip_runtime.h>

#define N_NODES 100000
#define N_EDGES 1200000
#define BK 64                     // nodes per bucket
#define NB 1563                   // ceil(100000/64)
#define CHUNK_E 4096
#define NBLK_E 293                // ceil(N_EDGES / CHUNK_E)
#define TOT_H (NB * NBLK_E)       // 457959
#define NSB2 ((TOT_H + 1023) / 1024)   // 448
#define CAP 1536                  // LDS edge-list capacity (expected ~768 +- 28)
#define ND1 3125                  // dense1 blocks (32 nodes each)

// Workspace layout (bytes), ~50.2 MB (hs_scan folded in-place into hist_g):
#define OFF_ROWPTR 0
#define OFF_HISTG  401408
#define OFF_BLK2   2234368
#define OFF_PAIRS  2236416
#define OFF_SORTED 7036928
#define OFF_Y1     11837440
#define OFF_H1     24637440

__device__ __forceinline__ unsigned short f2bf(float f) {
    unsigned u = __float_as_uint(f);
    unsigned r = (u + 0x7fffu + ((u >> 16) & 1u)) >> 16;   // RNE
    return (unsigned short)r;
}

// ---- K1: chunk_hist (blocks 0..292) + dense1 (blocks 293..3417) fused ----
// Round-6 structure: best of 8 variants (~85% of the 103 TF f32 roofline for
// dense1's 3.28 GFLOP). MFMA role-split variants (r4-r11) all lost; r13's
// dense2-fusion lost (256 scalar LDS reads/thread epilogue, 12.4M conflicts).
__global__ __launch_bounds__(256) void hist_dense1_kernel(
    const int* __restrict__ dst, int* __restrict__ hist_g,
    const float* __restrict__ x,
    const float* __restrict__ Wn, const float* __restrict__ Ws,
    const float* __restrict__ b,
    unsigned short* __restrict__ y1, float* __restrict__ z1)
{
    __shared__ float sx[32 * 64];   // 8 KB; hist part reuses as int h[NB] (1563 <= 2048)
    const int t = threadIdx.x;

    if (blockIdx.x < NBLK_E) {
        int* h = (int*)sx;
        const int e0 = blockIdx.x * CHUNK_E;
        const int e1 = min(e0 + CHUNK_E, N_EDGES);
        for (int i = t; i < NB; i += 256) h[i] = 0;
        __syncthreads();
        for (int e = e0 + t; e < e1; e += 256)
            atomicAdd(&h[dst[e] >> 6], 1);
        __syncthreads();
        for (int i = t; i < NB; i += 256)
            hist_g[i * NBLK_E + blockIdx.x] = h[i];
        return;
    }

    const int bid = blockIdx.x - NBLK_E;
    const int w = t >> 6;
    const int lane = t & 63;
    const int half = w >> 1;
    const int nsub = (w & 1) * 16;
    const int chunk = bid * 32;

    {
        const float4* gx = (const float4*)(x + (size_t)chunk * 64);
        float4* sx4 = (float4*)sx;
        sx4[t] = gx[t];
        sx4[t + 256] = gx[t + 256];
    }

    const float* W = half ? Ws : Wn;
    float wr[64];
#pragma unroll
    for (int k = 0; k < 64; ++k) wr[k] = W[k * 64 + lane];
    const float bj = half ? b[lane] : 0.f;

    __syncthreads();

#pragma unroll 2
    for (int m = 0; m < 16; ++m) {
        const int node = nsub + m;
        const float4* xr = (const float4*)(sx + node * 64);
        float a0 = 0.f, a1 = 0.f, a2 = 0.f, a3 = 0.f;
#pragma unroll
        for (int k4 = 0; k4 < 16; ++k4) {
            float4 v = xr[k4];
            a0 += v.x * wr[4 * k4 + 0];
            a1 += v.y * wr[4 * k4 + 1];
            a2 += v.z * wr[4 * k4 + 2];
            a3 += v.w * wr[4 * k4 + 3];
        }
        const float o = (a0 + a1) + (a2 + a3) + bj;
        const size_t gn = (size_t)(chunk + node);
        if (half) z1[gn * 64 + lane] = o;
        else      y1[gn * 64 + lane] = f2bf(o);
    }
}

// ---- K2: block-local scan of hist_g IN PLACE via wave-shuffle ----
__global__ __launch_bounds__(1024) void scan2_blocks_kernel(
    int* __restrict__ hist_g, int* __restrict__ blk2)
{
    __shared__ int wsum[16];
    const int t = threadIdx.x;
    const int i = blockIdx.x * 1024 + t;
    const int v = (i < TOT_H) ? hist_g[i] : 0;
    int inc = v;
#pragma unroll
    for (int off = 1; off < 64; off <<= 1) {
        int n = __shfl_up(inc, off);
        if ((t & 63) >= off) inc += n;
    }
    const int wid = t >> 6;                 // 0..15
    if ((t & 63) == 63) wsum[wid] = inc;
    __syncthreads();
    if (t < 16) {
        int s = wsum[t];
#pragma unroll
        for (int off = 1; off < 16; off <<= 1) {
            int n = __shfl_up(s, off);
            if (t >= off) s += n;
        }
        wsum[t] = s;
    }
    __syncthreads();
    const int base = (wid > 0) ? wsum[wid - 1] : 0;
    const int incl = inc + base;
    if (i < TOT_H) hist_g[i] = incl - v;    // exclusive
    if (t == 1023) blk2[blockIdx.x] = incl; // block total
}

// ---- K2b: single-block exclusive scan of blk2 IN PLACE (wave-shuffle) ----
__global__ __launch_bounds__(512) void tops_scan_kernel(int* __restrict__ blk2)
{
    __shared__ int wsum[8];
    const int t = threadIdx.x;
    const int v = (t < NSB2) ? blk2[t] : 0;
    int inc = v;
#pragma unroll
    for (int off = 1; off < 64; off <<= 1) {
        int n = __shfl_up(inc, off);
        if ((t & 63) >= off) inc += n;
    }
    const int wid = t >> 6;                 // 0..7
    if ((t & 63) == 63) wsum[wid] = inc;
    __syncthreads();
    if (t < 8) {
        int s = wsum[t];
#pragma unroll
        for (int off = 1; off < 8; off <<= 1) {
            int n = __shfl_up(s, off);
            if (t >= off) s += n;
        }
        wsum[t] = s;
    }
    __syncthreads();
    const int base = (wid > 0) ? wsum[wid - 1] : 0;
    if (t < NSB2) blk2[t] = inc + base - v; // exclusive prefix
}

// ---- K3: deterministic pair scatter (blk2 holds pre-scanned tops) ----
__global__ __launch_bounds__(512) void pair_scatter_kernel(
    const int* __restrict__ src, const int* __restrict__ dst,
    const int* __restrict__ hs_scan, const int* __restrict__ blk2,
    unsigned* __restrict__ pairs)
{
    __shared__ int base_s[NB];
    __shared__ int cur_s[NB];
    const int b = blockIdx.x;
    const int t = threadIdx.x;
    const int e0 = b * CHUNK_E;
    const int e1 = min(e0 + CHUNK_E, N_EDGES);

    for (int i = t; i < NB; i += 512) {
        int idx = i * NBLK_E + b;
        base_s[i] = hs_scan[idx] + blk2[idx >> 10];
        cur_s[i] = 0;
    }
    __syncthreads();
    for (int e = e0 + t; e < e1; e += 512) {
        int d = dst[e];
        int bk = d >> 6;
        int pos = base_s[bk] + atomicAdd(&cur_s[bk], 1);
        pairs[pos] = ((unsigned)src[e] << 6) | (unsigned)(d & 63);
    }
}

// ---- K4: fused bucket sort + gather1 (2 nodes/wave, 4 edge slots, z-prefetch;
//          wave-0 shfl scan; q-loop unroll 2 restored from r6) ----
__global__ __launch_bounds__(512) void fused_gather1_kernel(
    const unsigned short* __restrict__ y1,
    const unsigned* __restrict__ pairs,
    const int* __restrict__ hs_scan, const int* __restrict__ blk2,
    int* __restrict__ row_ptr, int* __restrict__ sorted_src,
    float* __restrict__ h1)
{
    __shared__ int slist[CAP];
    __shared__ int hist[BK];
    __shared__ int sc[BK];
    __shared__ int cur[BK];
    const int b = blockIdx.x;
    const int t = threadIdx.x;

    const int i0 = b * NBLK_E;
    const int start = hs_scan[i0] + blk2[i0 >> 10];
    const int end = (b == NB - 1) ? N_EDGES
                    : hs_scan[i0 + NBLK_E] + blk2[(i0 + NBLK_E) >> 10];
    const int cnt = end - start;
    const int node0 = b * BK;

    if (t < BK) hist[t] = 0;
    __syncthreads();
    for (int e = start + t; e < end; e += 512)
        atomicAdd(&hist[pairs[e] & 63u], 1);
    __syncthreads();

    // 64-bin inclusive scan by wave 0 (BK == wavefront size), no barriers
    int v = 0;
    if (t < BK) {
        v = hist[t];
        int inc = v;
#pragma unroll
        for (int off = 1; off < 64; off <<= 1) {
            int n = __shfl_up(inc, off);
            if (t >= off) inc += n;
        }
        sc[t] = inc;                        // inclusive
    }
    __syncthreads();
    const int excl = (t < BK) ? sc[t] - v : 0;
    if (t < BK && node0 + t < N_NODES) row_ptr[node0 + t] = start + excl;
    if (b == NB - 1 && t == 0) row_ptr[N_NODES] = N_EDGES;
    if (t < BK) cur[t] = excl;
    __syncthreads();

    const int wv = t >> 6;
    const int lane = t & 63;
    const int sub = lane >> 5;        // 2 nodes per wave
    const int sl = lane & 31;
    const int eg = sl >> 3;           // 4 edge slots
    const int fl = sl & 7;            // uint4 chunk of the 128 B y1 row

    if (cnt <= CAP) {
        for (int e = start + t; e < end; e += 512) {
            unsigned u = pairs[e];
            int p = atomicAdd(&cur[u & 63u], 1);
            slist[p] = (int)(u >> 6);
        }
        __syncthreads();
        for (int i = t; i < cnt; i += 512)
            sorted_src[start + i] = slist[i];
#pragma unroll 2
        for (int q = 0; q < 4; ++q) {
            const int node = wv * 8 + q * 2 + sub;
            const int gn = node0 + node;
            if (gn < N_NODES) {
            const int o = sc[node] - hist[node];
            const int dg = hist[node];
            float4* hp = (float4*)(h1 + (size_t)gn * 64);
            float4 z;
            if (eg < 2) z = hp[fl * 2 + eg];     // prefetch self-part row early
            float a0 = 0.f, a1 = 0.f, a2 = 0.f, a3 = 0.f;
            float a4 = 0.f, a5 = 0.f, a6 = 0.f, a7 = 0.f;
            for (int base = 0; base < dg; base += 8) {
                const int i0e = base + eg;
                const int i1e = base + 4 + eg;
                const bool v0 = i0e < dg, v1 = i1e < dg;
                uint4 r0, r1;
                if (v0) {
                    const int s = slist[o + i0e];
                    r0 = ((const uint4*)(y1 + (size_t)s * 64))[fl];
                }
                if (v1) {
                    const int s = slist[o + i1e];
                    r1 = ((const uint4*)(y1 + (size_t)s * 64))[fl];
                }
                if (v0) {
                    a0 += __uint_as_float(r0.x << 16);
                    a1 += __uint_as_float(r0.x & 0xffff0000u);
                    a2 += __uint_as_float(r0.y << 16);
                    a3 += __uint_as_float(r0.y & 0xffff0000u);
                    a4 += __uint_as_float(r0.z << 16);
                    a5 += __uint_as_float(r0.z & 0xffff0000u);
                    a6 += __uint_as_float(r0.w << 16);
                    a7 += __uint_as_float(r0.w & 0xffff0000u);
                }
                if (v1) {
                    a0 += __uint_as_float(r1.x << 16);
                    a1 += __uint_as_float(r1.x & 0xffff0000u);
                    a2 += __uint_as_float(r1.y << 16);
                    a3 += __uint_as_float(r1.y & 0xffff0000u);
                    a4 += __uint_as_float(r1.z << 16);
                    a5 += __uint_as_float(r1.z & 0xffff0000u);
                    a6 += __uint_as_float(r1.w << 16);
                    a7 += __uint_as_float(r1.w & 0xffff0000u);
                }
            }
#pragma unroll
            for (int d = 8; d <= 16; d <<= 1) {
                a0 += __shfl_xor(a0, d); a1 += __shfl_xor(a1, d);
                a2 += __shfl_xor(a2, d); a3 += __shfl_xor(a3, d);
                a4 += __shfl_xor(a4, d); a5 += __shfl_xor(a5, d);
                a6 += __shfl_xor(a6, d); a7 += __shfl_xor(a7, d);
            }
            const float invd = 1.0f / (float)max(dg, 1);
            if (eg == 0) {
                hp[fl * 2] = make_float4(fmaxf(z.x + a0 * invd, 0.f),
                                         fmaxf(z.y + a1 * invd, 0.f),
                                         fmaxf(z.z + a2 * invd, 0.f),
                                         fmaxf(z.w + a3 * invd, 0.f));
            } else if (eg == 1) {
                hp[fl * 2 + 1] = make_float4(fmaxf(z.x + a4 * invd, 0.f),
                                             fmaxf(z.y + a5 * invd, 0.f),
                                             fmaxf(z.z + a6 * invd, 0.f),
                                             fmaxf(z.w + a7 * invd, 0.f));
            }
            }
        }
    } else {
        // fallback (statistically unreachable): global two-phase sort + gather
        if (t < BK) cur[t] = start + excl;
        __syncthreads();
        for (int e = start + t; e < end; e += 512) {
            unsigned u = pairs[e];
            int p = atomicAdd(&cur[u & 63u], 1);
            sorted_src[p] = (int)(u >> 6);
        }
        __syncthreads();
        for (int q = 0; q < 4; ++q) {
            const int node = wv * 8 + q * 2 + sub;
            const int gn = node0 + node;
            if (gn < N_NODES) {
            const int o = start + sc[node] - hist[node];
            const int dg = hist[node];
            float4* hp = (float4*)(h1 + (size_t)gn * 64);
            float4 z;
            if (eg < 2) z = hp[fl * 2 + eg];
            float a0 = 0.f, a1 = 0.f, a2 = 0.f, a3 = 0.f;
            float a4 = 0.f, a5 = 0.f, a6 = 0.f, a7 = 0.f;
            for (int base = 0; base < dg; base += 4) {
                const int idx = base + eg;
                if (idx < dg) {
                    const int s = sorted_src[o + idx];
                    uint4 raw = ((const uint4*)(y1 + (size_t)s * 64))[fl];
                    a0 += __uint_as_float(raw.x << 16);
                    a1 += __uint_as_float(raw.x & 0xffff0000u);
                    a2 += __uint_as_float(raw.y << 16);
                    a3 += __uint_as_float(raw.y & 0xffff0000u);
                    a4 += __uint_as_float(raw.z << 16);
                    a5 += __uint_as_float(raw.z & 0xffff0000u);
                    a6 += __uint_as_float(raw.w << 16);
                    a7 += __uint_as_float(raw.w & 0xffff0000u);
                }
            }
#pragma unroll
            for (int d = 8; d <= 16; d <<= 1) {
                a0 += __shfl_xor(a0, d); a1 += __shfl_xor(a1, d);
                a2 += __shfl_xor(a2, d); a3 += __shfl_xor(a3, d);
                a4 += __shfl_xor(a4, d); a5 += __shfl_xor(a5, d);
                a6 += __shfl_xor(a6, d); a7 += __shfl_xor(a7, d);
            }
            const float invd = 1.0f / (float)max(dg, 1);
            if (eg == 0) {
                hp[fl * 2] = make_float4(fmaxf(z.x + a0 * invd, 0.f),
                                         fmaxf(z.y + a1 * invd, 0.f),
                                         fmaxf(z.z + a2 * invd, 0.f),
                                         fmaxf(z.w + a3 * invd, 0.f));
            } else if (eg == 1) {
                hp[fl * 2 + 1] = make_float4(fmaxf(z.x + a4 * invd, 0.f),
                                             fmaxf(z.y + a5 * invd, 0.f),
                                             fmaxf(z.z + a6 * invd, 0.f),
                                             fmaxf(z.w + a7 * invd, 0.f));
            }
            }
        }
    }
}

// ---- K5: dense2 (weights-in-lanes, r6 version: register weights + unroll 2) ----
__global__ __launch_bounds__(256) void dense2_kernel(
    const float* __restrict__ h1,
    const float* __restrict__ Wn, const float* __restrict__ Ws,
    const float* __restrict__ b,
    float* __restrict__ y2, float* __restrict__ out)
{
    __shared__ float sx[32 * 68];
    const int t = threadIdx.x;
    const int w = t >> 6;
    const int lane = t & 63;
    const int half = w >> 1;
    const int nsub = (w & 1) * 16;
    const int j = lane & 15;
    const int g = lane >> 4;
    const int chunk = blockIdx.x * 32;

    {
        const float4* gx = (const float4*)(h1 + (size_t)chunk * 64);
        float4* sx4 = (float4*)sx;
        int r0 = t >> 4, c0 = t & 15;
        sx4[r0 * 17 + c0] = gx[t];
        sx4[(r0 + 16) * 17 + c0] = gx[t + 256];
    }

    const float* W = half ? Ws : Wn;
    float wr[64];
#pragma unroll
    for (int k = 0; k < 64; ++k) wr[k] = W[k * 16 + j];
    const float bj = half ? b[j] : 0.f;

    __syncthreads();

#pragma unroll 2
    for (int q = 0; q < 4; ++q) {
        const int node = nsub + q * 4 + g;
        const float4* xr = (const float4*)(sx + node * 68);
        float a0 = 0.f, a1 = 0.f, a2 = 0.f, a3 = 0.f;
#pragma unroll
        for (int k4 = 0; k4 < 16; ++k4) {
            float4 v = xr[k4];
            a0 += v.x * wr[4 * k4 + 0];
            a1 += v.y * wr[4 * k4 + 1];
            a2 += v.z * wr[4 * k4 + 2];
            a3 += v.w * wr[4 * k4 + 3];
        }
        const float o = (a0 + a1) + (a2 + a3) + bj;
        const size_t gn = (size_t)(chunk + node);
        if (half) out[gn * 16 + j] = o;
        else      y2[gn * 16 + j] = o;
    }
}

// ---- K6: gather2 — 4 nodes per wave (16 lanes/node), out-row prefetched ----
__global__ __launch_bounds__(256) void gather2_kernel(
    const float* __restrict__ y2,
    const int* __restrict__ row_ptr,
    const int* __restrict__ sorted_src,
    float* __restrict__ out)
{
    const int wv = threadIdx.x >> 6;
    const int lane = threadIdx.x & 63;
    const int sub = lane >> 4;        // node slot 0..3
    const int sl = lane & 15;         // lane within node group
    const int eg = sl >> 2;           // edge slot 0..3
    const int fl = sl & 3;            // float4 chunk of 16-f32 row

    const int n = blockIdx.x * 16 + wv * 4 + sub;   // grid 6250 -> exact
    const int start = row_ptr[n];
    const int deg = row_ptr[n + 1] - start;

    float4* op = (float4*)(out + (size_t)n * 16);
    float4 z;
    if (eg == 0) z = op[fl];          // prefetch self-part row early

    float4 acc = make_float4(0.f, 0.f, 0.f, 0.f);
    for (int base = 0; base < deg; base += 16) {
        int eid = 0;
        if (base + sl < deg) eid = sorted_src[start + base + sl];
#pragma unroll
        for (int jj = 0; jj < 16; jj += 4) {
            const int idx = jj + eg;
            const int s = __shfl(eid, sub * 16 + idx);
            if (base + idx < deg) {
                float4 v = ((const float4*)(y2 + (size_t)s * 16))[fl];
                acc.x += v.x; acc.y += v.y; acc.z += v.z; acc.w += v.w;
            }
        }
    }
#pragma unroll
    for (int d = 4; d <= 8; d <<= 1) {
        acc.x += __shfl_xor(acc.x, d); acc.y += __shfl_xor(acc.y, d);
        acc.z += __shfl_xor(acc.z, d); acc.w += __shfl_xor(acc.w, d);
    }
    const float invd = 1.0f / (float)max(deg, 1);
    if (eg == 0) {
        op[fl] = make_float4(z.x + acc.x * invd, z.y + acc.y * invd,
                             z.z + acc.z * invd, z.w + acc.w * invd);
    }
}

extern "C" void kernel_launch(void* const* d_in, const int* in_sizes, int n_in,
                              void* d_out, int out_size, void* d_ws, size_t ws_size,
                              hipStream_t stream) {
    const float* x   = (const float*)d_in[0];
    const int*   src = (const int*)d_in[1];
    const int*   dst = (const int*)d_in[2];
    const float* W1s = (const float*)d_in[3];
    const float* W1n = (const float*)d_in[4];
    const float* b1  = (const float*)d_in[5];
    const float* W2s = (const float*)d_in[6];
    const float* W2n = (const float*)d_in[7];
    const float* b2  = (const float*)d_in[8];
    float* out = (float*)d_out;

    char* ws = (char*)d_ws;
    int* row_ptr    = (int*)(ws + OFF_ROWPTR);
    int* hist_g     = (int*)(ws + OFF_HISTG);   // scanned in place by K2
    int* blk2       = (int*)(ws + OFF_BLK2);    // raw sums -> K2b scans in place
    unsigned* pairs = (unsigned*)(ws + OFF_PAIRS);
    int* sorted_src = (int*)(ws + OFF_SORTED);
    unsigned short* y1 = (unsigned short*)(ws + OFF_Y1);
    float* y2       = (float*)(ws + OFF_Y1);   // reuses y1 space after fused_gather1
    float* h1       = (float*)(ws + OFF_H1);

    hist_dense1_kernel<<<NBLK_E + ND1, 256, 0, stream>>>(
        dst, hist_g, x, W1n, W1s, b1, y1, h1);
    scan2_blocks_kernel<<<NSB2, 1024, 0, stream>>>(hist_g, blk2);
    tops_scan_kernel<<<1, 512, 0, stream>>>(blk2);
    pair_scatter_kernel<<<NBLK_E, 512, 0, stream>>>(src, dst, hist_g, blk2, pairs);
    fused_gather1_kernel<<<NB, 512, 0, stream>>>(y1, pairs, hist_g, blk2,
                                                 row_ptr, sorted_src, h1);
    dense2_kernel<<<ND1, 256, 0, stream>>>(h1, W2n, W2s, b2, y2, out);
    gather2_kernel<<<N_NODES / 16, 256, 0, stream>>>(y2, row_ptr, sorted_src, out);
}